// Round 4
// baseline (213.303 us; speedup 1.0000x reference)
//
#include <hip/hip_runtime.h>

// NT-Xent loss, fused + symmetric + 8-phase 256^2 GEMM:
//   1. row-normalize f32 -> bf16 Z (zeroes accumulators)
//   2. triangular-grid (32x33/2 = 528 blocks) bf16 GEMM C = Z Z^T, 256^2 tile,
//      8-wave 8-phase schedule (T2 swizzle + T3/T4 counted vmcnt + T5 setprio),
//      fused exp-rowsum epilogue, fixed lse shift = 10 (diag == 10); off-diag
//      tiles contribute row- AND col-axis sums (symmetry halves MFMA work).
//   3. per-row v_i = 10 + log(sumexp_i) - 10*dot(z_i,z_0), block-partial ->
//      double atomicAdd; 4. store mean.

typedef unsigned short ushort_t;
typedef __attribute__((ext_vector_type(8))) short short8;
typedef __attribute__((ext_vector_type(4))) float f32x4;

#define N_ROWS 8192
#define N_DIM  1024

__device__ __forceinline__ float bf2f(ushort_t u) {
    return __uint_as_float(((unsigned int)u) << 16);
}
__device__ __forceinline__ ushort_t f2bf(float f) {
    unsigned int u = __float_as_uint(f);
    return (ushort_t)((u + 0x7FFFu + ((u >> 16) & 1u)) >> 16);  // RNE
}

// ---------------------------------------------------------------- kernel 1
__global__ __launch_bounds__(256) void k_normalize(const float* __restrict__ X,
                                                   ushort_t* __restrict__ Z,
                                                   float* __restrict__ sumexp,
                                                   double* __restrict__ dsum) {
    const int row  = blockIdx.x;
    const int lane = threadIdx.x & 63;
    const int w    = threadIdx.x >> 6;

    float4 v = ((const float4*)(X + (size_t)row * N_DIM))[threadIdx.x];
    float ss = v.x * v.x + v.y * v.y + v.z * v.z + v.w * v.w;
    #pragma unroll
    for (int off = 32; off; off >>= 1) ss += __shfl_down(ss, off);

    __shared__ float wsum[4];
    if (lane == 0) wsum[w] = ss;
    __syncthreads();
    float inv = 1.0f / fmaxf(sqrtf(wsum[0] + wsum[1] + wsum[2] + wsum[3]), 1e-8f);

    ushort4 o;
    o.x = f2bf(v.x * inv);
    o.y = f2bf(v.y * inv);
    o.z = f2bf(v.z * inv);
    o.w = f2bf(v.w * inv);
    ((ushort4*)(Z + (size_t)row * N_DIM))[threadIdx.x] = o;

    if (threadIdx.x == 0) sumexp[row] = 0.0f;
    if (row == 0 && threadIdx.x == 0) *dsum = 0.0;
}

// ---------------------------------------------------------------- kernel 2
// LDS map (ushort idx): A[dbuf][half] @ ((d*2+h)*8192), B @ 32768 + same.
// Half-tile = 128 rows x 64 cols bf16 = 16 KB. Swizzle: 16B unit cu = cl ^ (rl&7)
// (T2); staging pre-swizzles the GLOBAL source so gload_lds dest stays linear.
#define LDSA(d, h) (((d)*2 + (h)) * 8192)
#define LDSB(d, h) (32768 + ((d)*2 + (h)) * 8192)

#define STAGE(baseoff, panel, h, tt) do {                                         \
    _Pragma("unroll")                                                             \
    for (int p_ = 0; p_ < 2; ++p_) {                                              \
        int rl_ = (p_*8 + w)*8 + srow;                                            \
        const ushort_t* src_ = Z + (size_t)((panel) + (h)*128 + rl_) * N_DIM      \
                                 + (tt)*64 + scol*8;                              \
        __builtin_amdgcn_global_load_lds(                                         \
            (const __attribute__((address_space(1))) void*)src_,                  \
            (__attribute__((address_space(3))) void*)&sh[(baseoff) + (p_*8 + w)*512], \
            16, 0, 0);                                                            \
    }                                                                             \
} while (0)

#define READ_A(d, q) do {                                                         \
    _Pragma("unroll")                                                             \
    for (int mi_ = 0; mi_ < 2; ++mi_)                                             \
        _Pragma("unroll")                                                         \
        for (int ks_ = 0; ks_ < 2; ++ks_) {                                       \
            int rl_ = ((q)*2 + mi_)*16 + lrow;                                    \
            int cu_ = (ks_*4 + kq) ^ (rl_ & 7);                                   \
            afr[mi_][ks_] = *(const short8*)&sh[LDSA(d, wr) + rl_*64 + cu_*8];    \
        }                                                                         \
} while (0)

#define READ_B(d) do {                                                            \
    _Pragma("unroll")                                                             \
    for (int n_ = 0; n_ < 4; ++n_)                                                \
        _Pragma("unroll")                                                         \
        for (int ks_ = 0; ks_ < 2; ++ks_) {                                       \
            int rl_ = (wc & 1)*64 + n_*16 + lrow;                                 \
            int cu_ = (ks_*4 + kq) ^ (rl_ & 7);                                   \
            bfr[n_][ks_] = *(const short8*)&sh[LDSB(d, wc >> 1) + rl_*64 + cu_*8]; \
        }                                                                         \
} while (0)

#define MFMA_Q(q) do {                                                            \
    __builtin_amdgcn_s_setprio(1);                                                \
    _Pragma("unroll")                                                             \
    for (int mi_ = 0; mi_ < 2; ++mi_)                                             \
        _Pragma("unroll")                                                         \
        for (int n_ = 0; n_ < 4; ++n_) {                                          \
            f32x4 t_ = __builtin_amdgcn_mfma_f32_16x16x32_bf16(                   \
                afr[mi_][0], bfr[n_][0], acc[(q)*2 + mi_][n_], 0, 0, 0);          \
            acc[(q)*2 + mi_][n_] = __builtin_amdgcn_mfma_f32_16x16x32_bf16(       \
                afr[mi_][1], bfr[n_][1], t_, 0, 0, 0);                            \
        }                                                                         \
    __builtin_amdgcn_s_setprio(0);                                                \
} while (0)

#define BAR()    __builtin_amdgcn_s_barrier()
#define VMCNT4() asm volatile("s_waitcnt vmcnt(4)" ::: "memory")
#define VMCNT0() asm volatile("s_waitcnt vmcnt(0)" ::: "memory")
#define SBAR0()  __builtin_amdgcn_sched_barrier(0)

__global__ __launch_bounds__(512, 2) void k_gemm_lse(const ushort_t* __restrict__ Z,
                                                     float* __restrict__ sumexp) {
    __shared__ __align__(16) ushort_t sh[65536];  // 128 KiB

    const int tid  = threadIdx.x;
    const int lane = tid & 63;
    const int w    = tid >> 6;      // wave 0..7
    const int wr   = w >> 2;        // 0..1 (M)
    const int wc   = w & 3;         // 0..3 (N)
    const int lrow = lane & 15;
    const int kq   = lane >> 4;
    const int srow = lane >> 3;            // staging row sub-index 0..7
    const int scol = (lane & 7) ^ srow;    // pre-swizzled source unit

    // triangular decode (32 blocks/dim) with XCD chunking (528 = 8*66)
    int t = (int)blockIdx.x;
    t = (t & 7) * 66 + (t >> 3);
    int bi = (int)((sqrtf(8.0f * (float)t + 1.0f) - 1.0f) * 0.5f);
    while ((bi + 1) * (bi + 2) / 2 <= t) ++bi;
    while (bi * (bi + 1) / 2 > t) --bi;
    const int bj = t - bi * (bi + 1) / 2;
    const bool diag = (bi == bj);
    const int r0 = bi * 256, c0 = bj * 256;

    f32x4  acc[8][4] = {};
    short8 afr[2][2], bfr[4][2];

    // prologue: tile0 -> d0 (B0,B1,A0,A1), tile1's B -> d1 (B0,B1)
    STAGE(LDSB(0,0), c0, 0, 0);
    STAGE(LDSB(0,1), c0, 1, 0);
    STAGE(LDSA(0,0), r0, 0, 0);
    STAGE(LDSA(0,1), r0, 1, 0);
    STAGE(LDSB(1,0), c0, 0, 1);
    STAGE(LDSB(1,1), c0, 1, 1);
    VMCNT4();        // first 8 loads (all of d0) complete
    BAR();
    SBAR0();

    #pragma unroll 1
    for (int i = 0; i < 7; ++i) {
        const int t1 = 2*i + 1, t2 = 2*i + 2, t3 = 2*i + 3;
        // ph0..3: compute d0 (tile 2i); stage d1.A(t1), d0.B(t2)
        READ_B(0); READ_A(0,0); STAGE(LDSA(1,0), r0, 0, t1); BAR(); MFMA_Q(0); BAR();
        READ_A(0,1);            STAGE(LDSA(1,1), r0, 1, t1); BAR(); MFMA_Q(1); BAR();
        READ_A(0,2);            STAGE(LDSB(0,0), c0, 0, t2); BAR(); MFMA_Q(2); BAR();
        READ_A(0,3);            STAGE(LDSB(0,1), c0, 1, t2); BAR(); MFMA_Q(3);
        VMCNT4();  // d1.B(t1) [i-1 ph6/7] + d1.A(t1) [ph0/1] complete
        BAR(); SBAR0();
        // ph4..7: compute d1 (tile 2i+1); stage d0.A(t2), d1.B(t3)
        READ_B(1); READ_A(1,0); STAGE(LDSA(0,0), r0, 0, t2); BAR(); MFMA_Q(0); BAR();
        READ_A(1,1);            STAGE(LDSA(0,1), r0, 1, t2); BAR(); MFMA_Q(1); BAR();
        READ_A(1,2);            STAGE(LDSB(1,0), c0, 0, t3); BAR(); MFMA_Q(2); BAR();
        READ_A(1,3);            STAGE(LDSB(1,1), c0, 1, t3); BAR(); MFMA_Q(3);
        VMCNT4();  // d0.B(t2) [ph2/3] + d0.A(t2) [ph4/5] complete
        BAR(); SBAR0();
    }

    // epilogue iteration: tiles 14 (d0) and 15 (d1); only d1.A(15) still staged
    READ_B(0); READ_A(0,0); STAGE(LDSA(1,0), r0, 0, 15); BAR(); MFMA_Q(0); BAR();
    READ_A(0,1);            STAGE(LDSA(1,1), r0, 1, 15); BAR(); MFMA_Q(1); BAR();
    READ_A(0,2);                                         BAR(); MFMA_Q(2); BAR();
    READ_A(0,3); MFMA_Q(3); VMCNT0(); BAR(); SBAR0();
    READ_B(1); READ_A(1,0); BAR(); MFMA_Q(0); BAR();
    READ_A(1,1);            BAR(); MFMA_Q(1); BAR();
    READ_A(1,2);            BAR(); MFMA_Q(2); BAR();
    READ_A(1,3);            MFMA_Q(3);

    // ---- fused epilogue: e = exp(10c - 10); row sums always, col sums if !diag
    // C/D frag layout: col = lane&15 (lrow), row = kq*4 + r.
    float rp[8][4];
    float cp[4] = {0.f, 0.f, 0.f, 0.f};
    #pragma unroll
    for (int m = 0; m < 8; ++m)
        #pragma unroll
        for (int r = 0; r < 4; ++r) rp[m][r] = 0.f;

    #pragma unroll
    for (int m = 0; m < 8; ++m)
        #pragma unroll
        for (int n = 0; n < 4; ++n)
            #pragma unroll
            for (int r = 0; r < 4; ++r) {
                float e = __expf(acc[m][n][r] * 10.0f - 10.0f);
                rp[m][r] += e;
                cp[n]    += e;
            }

    #pragma unroll
    for (int m = 0; m < 8; ++m) {
        #pragma unroll
        for (int off = 1; off < 16; off <<= 1)
            #pragma unroll
            for (int r = 0; r < 4; ++r) rp[m][r] += __shfl_xor(rp[m][r], off);
        if (lrow == 0) {
            int rowbase = r0 + wr * 128 + m * 16 + kq * 4;
            #pragma unroll
            for (int r = 0; r < 4; ++r) atomicAdd(&sumexp[rowbase + r], rp[m][r]);
        }
    }

    if (!diag) {
        #pragma unroll
        for (int n = 0; n < 4; ++n) {
            cp[n] += __shfl_xor(cp[n], 16);
            cp[n] += __shfl_xor(cp[n], 32);
        }
        if (kq == 0) {
            #pragma unroll
            for (int n = 0; n < 4; ++n)
                atomicAdd(&sumexp[c0 + wc * 64 + n * 16 + lrow], cp[n]);
        }
    }
}

// ---------------------------------------------------------------- kernel 3
// 4 waves/block, wave per row: v = 10 + log(sumexp) - 10*dot(z_i, z_0);
// block partial -> one double atomicAdd.
__global__ __launch_bounds__(256) void k_finalize(const ushort_t* __restrict__ Z,
                                                  const float* __restrict__ sumexp,
                                                  double* __restrict__ dsum) {
    const int lane = threadIdx.x & 63;
    const int wid  = threadIdx.x >> 6;
    const int row  = blockIdx.x * 4 + wid;

    const ushort_t* zi = Z + (size_t)row * N_DIM + lane * 16;
    const ushort_t* z0 = Z + lane * 16;
    float dot = 0.0f;
    #pragma unroll
    for (int c = 0; c < 2; ++c) {
        short8 a = *(const short8*)(zi + c * 8);
        short8 b = *(const short8*)(z0 + c * 8);
        #pragma unroll
        for (int e = 0; e < 8; ++e)
            dot += bf2f((ushort_t)a[e]) * bf2f((ushort_t)b[e]);
    }
    #pragma unroll
    for (int off = 32; off; off >>= 1) dot += __shfl_down(dot, off);

    __shared__ float bs[4];
    if (lane == 0) bs[wid] = 10.0f + logf(sumexp[row]) - 10.0f * dot;
    __syncthreads();
    if (threadIdx.x == 0)
        atomicAdd(dsum, (double)(bs[0] + bs[1] + bs[2] + bs[3]));
}

// ---------------------------------------------------------------- kernel 4
__global__ void k_store(const double* __restrict__ dsum, float* __restrict__ out) {
    out[0] = (float)(*dsum * (1.0 / (double)N_ROWS));
}

// ----------------------------------------------------------------
extern "C" void kernel_launch(void* const* d_in, const int* in_sizes, int n_in,
                              void* d_out, int out_size, void* d_ws, size_t ws_size,
                              hipStream_t stream) {
    const float* X = (const float*)d_in[0];
    float* out = (float*)d_out;

    // ws: Z bf16 [8192*1024] (16MB) | sumexp f32[8192] | dsum double
    ushort_t* Z      = (ushort_t*)d_ws;
    float*    sumexp = (float*)((char*)d_ws + (size_t)N_ROWS * N_DIM * 2);
    double*   dsum   = (double*)((char*)d_ws + (size_t)N_ROWS * N_DIM * 2 + N_ROWS * 4);

    k_normalize<<<N_ROWS, 256, 0, stream>>>(X, Z, sumexp, dsum);

    const int nblk = 32 * 33 / 2;  // 528 triangular 256^2 tiles
    k_gemm_lse<<<nblk, 512, 0, stream>>>(Z, sumexp);

    k_finalize<<<N_ROWS / 4, 256, 0, stream>>>(Z, sumexp, dsum);
    k_store<<<1, 1, 0, stream>>>(dsum, out);
}

// Round 6
// 205.808 us; speedup vs baseline: 1.0364x; 1.0364x over previous
//
#include <hip/hip_runtime.h>

// NT-Xent loss, fused + symmetric + 8-phase 256^2 GEMM (template-verbatim
// per-phase fencing):
//   1. row-normalize f32 -> bf16 Z (wave per row; zeroes accumulators)
//   2. triangular-grid (528 blocks) bf16 GEMM C = Z Z^T, 256^2 tile, 8-wave
//      8-phase schedule (T2 swizzle + counted vmcnt + per-phase lgkmcnt(0)
//      + sched_barrier + setprio), fused exp-rowsum epilogue, fixed lse
//      shift = 10; off-diag tiles contribute row- AND col-axis sums.
//   3. per-row v_i = 10 + log(sumexp_i) - 10*dot(z_i,z_0) -> double atomicAdd
//   4. store mean.

typedef unsigned short ushort_t;
typedef __attribute__((ext_vector_type(8))) short short8;
typedef __attribute__((ext_vector_type(4))) float f32x4;

#define N_ROWS 8192
#define N_DIM  1024

__device__ __forceinline__ float bf2f(ushort_t u) {
    return __uint_as_float(((unsigned int)u) << 16);
}
__device__ __forceinline__ ushort_t f2bf(float f) {
    unsigned int u = __float_as_uint(f);
    return (ushort_t)((u + 0x7FFFu + ((u >> 16) & 1u)) >> 16);  // RNE
}

// ---------------------------------------------------------------- kernel 1
// Wave per row: 64 lanes x float4 = 1024 f32 = one full row. Pure shuffle
// reduce (no LDS / syncthreads). 4 rows per 256-thread block.
__global__ __launch_bounds__(256) void k_normalize(const float* __restrict__ X,
                                                   ushort_t* __restrict__ Z,
                                                   float* __restrict__ sumexp,
                                                   double* __restrict__ dsum) {
    const int lane = threadIdx.x & 63;
    const int wid  = threadIdx.x >> 6;
    const int row  = blockIdx.x * 4 + wid;

    float4 v = ((const float4*)(X + (size_t)row * N_DIM))[lane];
    float ss = v.x * v.x + v.y * v.y + v.z * v.z + v.w * v.w;
    #pragma unroll
    for (int off = 32; off; off >>= 1) ss += __shfl_xor(ss, off);
    float inv = 1.0f / fmaxf(sqrtf(ss), 1e-8f);

    ushort4 o;
    o.x = f2bf(v.x * inv);
    o.y = f2bf(v.y * inv);
    o.z = f2bf(v.z * inv);
    o.w = f2bf(v.w * inv);
    ((ushort4*)(Z + (size_t)row * N_DIM))[lane] = o;

    if (lane == 0) sumexp[row] = 0.0f;
    if (row == 0 && lane == 0) *dsum = 0.0;
}

// ---------------------------------------------------------------- kernel 2
// LDS map (ushort idx): A[dbuf][half] @ ((d*2+h)*8192), B @ 32768 + same.
// Half-tile = 128 rows x 64 cols bf16 = 16 KB. Swizzle: 16B unit cu = cl ^ (rl&7)
// (T2); staging pre-swizzles the GLOBAL source so gload_lds dest stays linear.
#define LDSA(d, h) (((d)*2 + (h)) * 8192)
#define LDSB(d, h) (32768 + ((d)*2 + (h)) * 8192)

#define STAGE(baseoff, panel, h, tt) do {                                         \
    _Pragma("unroll")                                                             \
    for (int p_ = 0; p_ < 2; ++p_) {                                              \
        int rl_ = (p_*8 + w)*8 + srow;                                            \
        const ushort_t* src_ = Z + (size_t)((panel) + (h)*128 + rl_) * N_DIM      \
                                 + (tt)*64 + scol*8;                              \
        __builtin_amdgcn_global_load_lds(                                         \
            (const __attribute__((address_space(1))) void*)src_,                  \
            (__attribute__((address_space(3))) void*)&sh[(baseoff) + (p_*8 + w)*512], \
            16, 0, 0);                                                            \
    }                                                                             \
} while (0)

#define READ_A(d, q) do {                                                         \
    _Pragma("unroll")                                                             \
    for (int mi_ = 0; mi_ < 2; ++mi_)                                             \
        _Pragma("unroll")                                                         \
        for (int ks_ = 0; ks_ < 2; ++ks_) {                                       \
            int rl_ = ((q)*2 + mi_)*16 + lrow;                                    \
            int cu_ = (ks_*4 + kq) ^ (rl_ & 7);                                   \
            afr[mi_][ks_] = *(const short8*)&sh[LDSA(d, wr) + rl_*64 + cu_*8];    \
        }                                                                         \
} while (0)

#define READ_B(d) do {                                                            \
    _Pragma("unroll")                                                             \
    for (int n_ = 0; n_ < 4; ++n_)                                                \
        _Pragma("unroll")                                                         \
        for (int ks_ = 0; ks_ < 2; ++ks_) {                                       \
            int rl_ = (wc & 1)*64 + n_*16 + lrow;                                 \
            int cu_ = (ks_*4 + kq) ^ (rl_ & 7);                                   \
            bfr[n_][ks_] = *(const short8*)&sh[LDSB(d, wc >> 1) + rl_*64 + cu_*8]; \
        }                                                                         \
} while (0)

#define MFMA_Q(q) do {                                                            \
    __builtin_amdgcn_s_setprio(1);                                                \
    _Pragma("unroll")                                                             \
    for (int mi_ = 0; mi_ < 2; ++mi_)                                             \
        _Pragma("unroll")                                                         \
        for (int n_ = 0; n_ < 4; ++n_) {                                          \
            f32x4 t_ = __builtin_amdgcn_mfma_f32_16x16x32_bf16(                   \
                afr[mi_][0], bfr[n_][0], acc[(q)*2 + mi_][n_], 0, 0, 0);          \
            acc[(q)*2 + mi_][n_] = __builtin_amdgcn_mfma_f32_16x16x32_bf16(       \
                afr[mi_][1], bfr[n_][1], t_, 0, 0, 0);                            \
        }                                                                         \
    __builtin_amdgcn_s_setprio(0);                                                \
} while (0)

#define BAR()    __builtin_amdgcn_s_barrier()
#define VMCNT4() asm volatile("s_waitcnt vmcnt(4)" ::: "memory")
#define VMCNT0() asm volatile("s_waitcnt vmcnt(0)" ::: "memory")
#define SBAR0()  __builtin_amdgcn_sched_barrier(0)
#define LGKM0()  asm volatile("s_waitcnt lgkmcnt(0)" ::: "memory")
#define LGKM8()  asm volatile("s_waitcnt lgkmcnt(8)" ::: "memory")

// per-phase tail: barrier -> drain LDS reads -> fence -> MFMA cluster -> barrier
#define PHASE_MFMA(q) do { BAR(); LGKM0(); SBAR0(); MFMA_Q(q); BAR(); } while (0)

__global__ __launch_bounds__(512, 2) void k_gemm_lse(const ushort_t* __restrict__ Z,
                                                     float* __restrict__ sumexp) {
    __shared__ __align__(16) ushort_t sh[65536];  // 128 KiB

    const int tid  = threadIdx.x;
    const int lane = tid & 63;
    const int w    = tid >> 6;      // wave 0..7
    const int wr   = w >> 2;        // 0..1 (M)
    const int wc   = w & 3;         // 0..3 (N)
    const int lrow = lane & 15;
    const int kq   = lane >> 4;
    const int srow = lane >> 3;            // staging row sub-index 0..7
    const int scol = (lane & 7) ^ srow;    // pre-swizzled source unit

    // triangular decode (32 blocks/dim) with XCD chunking (528 = 8*66)
    int t = (int)blockIdx.x;
    t = (t & 7) * 66 + (t >> 3);
    int bi = (int)((sqrtf(8.0f * (float)t + 1.0f) - 1.0f) * 0.5f);
    while ((bi + 1) * (bi + 2) / 2 <= t) ++bi;
    while (bi * (bi + 1) / 2 > t) --bi;
    const int bj = t - bi * (bi + 1) / 2;
    const bool diag = (bi == bj);
    const int r0 = bi * 256, c0 = bj * 256;

    f32x4  acc[8][4] = {};
    short8 afr[2][2], bfr[4][2];

    // prologue: tile0 -> d0 (B0,B1,A0,A1), tile1's B -> d1 (B0,B1); 12 loads,
    // vmcnt(4) completes the 8 oldest (= all of d0), keeps d1.B in flight.
    STAGE(LDSB(0,0), c0, 0, 0);
    STAGE(LDSB(0,1), c0, 1, 0);
    STAGE(LDSA(0,0), r0, 0, 0);
    STAGE(LDSA(0,1), r0, 1, 0);
    STAGE(LDSB(1,0), c0, 0, 1);
    STAGE(LDSB(1,1), c0, 1, 1);
    VMCNT4();
    BAR();
    SBAR0();

    #pragma unroll 1
    for (int i = 0; i < 7; ++i) {
        const int t1 = 2*i + 1, t2 = 2*i + 2, t3 = 2*i + 3;
        // ---- ph0..3: compute d0 (tile 2i); stage d1.A(t1), d0.B(t2)
        READ_B(0); READ_A(0,0); STAGE(LDSA(1,0), r0, 0, t1); LGKM8();
        PHASE_MFMA(0);
        READ_A(0,1);            STAGE(LDSA(1,1), r0, 1, t1);
        PHASE_MFMA(1);
        READ_A(0,2);            STAGE(LDSB(0,0), c0, 0, t2);
        PHASE_MFMA(2);
        READ_A(0,3);            STAGE(LDSB(0,1), c0, 1, t2);
        BAR(); LGKM0(); SBAR0(); MFMA_Q(3);
        VMCNT4();  // 12 in flight -> 8 oldest (d1.B(t1)x4 + d1.A(t1)x4) done
        BAR(); SBAR0();
        // ---- ph4..7: compute d1 (tile 2i+1); stage d0.A(t2), d1.B(t3)
        READ_B(1); READ_A(1,0); STAGE(LDSA(0,0), r0, 0, t2); LGKM8();
        PHASE_MFMA(0);
        READ_A(1,1);            STAGE(LDSA(0,1), r0, 1, t2);
        PHASE_MFMA(1);
        READ_A(1,2);            STAGE(LDSB(1,0), c0, 0, t3);
        PHASE_MFMA(2);
        READ_A(1,3);            STAGE(LDSB(1,1), c0, 1, t3);
        BAR(); LGKM0(); SBAR0(); MFMA_Q(3);
        VMCNT4();  // 8 oldest (d0.B(t2)x4 + d0.A(t2)x4) done
        BAR(); SBAR0();
    }

    // epilogue iteration: tiles 14 (d0) and 15 (d1); only d1.A(15) still staged
    READ_B(0); READ_A(0,0); STAGE(LDSA(1,0), r0, 0, 15); LGKM8();
    PHASE_MFMA(0);
    READ_A(0,1);            STAGE(LDSA(1,1), r0, 1, 15);
    PHASE_MFMA(1);
    READ_A(0,2);
    PHASE_MFMA(2);
    READ_A(0,3);
    BAR(); LGKM0(); SBAR0(); MFMA_Q(3); VMCNT0(); BAR(); SBAR0();
    READ_B(1); READ_A(1,0);
    PHASE_MFMA(0);
    READ_A(1,1);
    PHASE_MFMA(1);
    READ_A(1,2);
    PHASE_MFMA(2);
    READ_A(1,3);
    LGKM0(); SBAR0(); MFMA_Q(3);

    // ---- fused epilogue: e = exp(10c - 10); row sums always, col sums if !diag
    // C/D frag layout: col = lane&15 (lrow), row = kq*4 + r.
    float rp[8][4];
    float cp[4] = {0.f, 0.f, 0.f, 0.f};
    #pragma unroll
    for (int m = 0; m < 8; ++m)
        #pragma unroll
        for (int r = 0; r < 4; ++r) rp[m][r] = 0.f;

    #pragma unroll
    for (int m = 0; m < 8; ++m)
        #pragma unroll
        for (int n = 0; n < 4; ++n)
            #pragma unroll
            for (int r = 0; r < 4; ++r) {
                float e = __expf(acc[m][n][r] * 10.0f - 10.0f);
                rp[m][r] += e;
                cp[n]    += e;
            }

    #pragma unroll
    for (int m = 0; m < 8; ++m) {
        #pragma unroll
        for (int off = 1; off < 16; off <<= 1)
            #pragma unroll
            for (int r = 0; r < 4; ++r) rp[m][r] += __shfl_xor(rp[m][r], off);
        if (lrow == 0) {
            int rowbase = r0 + wr * 128 + m * 16 + kq * 4;
            #pragma unroll
            for (int r = 0; r < 4; ++r) atomicAdd(&sumexp[rowbase + r], rp[m][r]);
        }
    }

    if (!diag) {
        #pragma unroll
        for (int n = 0; n < 4; ++n) {
            cp[n] += __shfl_xor(cp[n], 16);
            cp[n] += __shfl_xor(cp[n], 32);
        }
        if (kq == 0) {
            #pragma unroll
            for (int n = 0; n < 4; ++n)
                atomicAdd(&sumexp[c0 + wc * 64 + n * 16 + lrow], cp[n]);
        }
    }
}

// ---------------------------------------------------------------- kernel 3
// 4 waves/block, wave per row: v = 10 + log(sumexp) - 10*dot(z_i, z_0);
// block partial -> one double atomicAdd.
__global__ __launch_bounds__(256) void k_finalize(const ushort_t* __restrict__ Z,
                                                  const float* __restrict__ sumexp,
                                                  double* __restrict__ dsum) {
    const int lane = threadIdx.x & 63;
    const int wid  = threadIdx.x >> 6;
    const int row  = blockIdx.x * 4 + wid;

    const ushort_t* zi = Z + (size_t)row * N_DIM + lane * 16;
    const ushort_t* z0 = Z + lane * 16;
    float dot = 0.0f;
    #pragma unroll
    for (int c = 0; c < 2; ++c) {
        short8 a = *(const short8*)(zi + c * 8);
        short8 b = *(const short8*)(z0 + c * 8);
        #pragma unroll
        for (int e = 0; e < 8; ++e)
            dot += bf2f((ushort_t)a[e]) * bf2f((ushort_t)b[e]);
    }
    #pragma unroll
    for (int off = 32; off; off >>= 1) dot += __shfl_down(dot, off);

    __shared__ float bs[4];
    if (lane == 0) bs[wid] = 10.0f + logf(sumexp[row]) - 10.0f * dot;
    __syncthreads();
    if (threadIdx.x == 0)
        atomicAdd(dsum, (double)(bs[0] + bs[1] + bs[2] + bs[3]));
}

// ---------------------------------------------------------------- kernel 4
__global__ void k_store(const double* __restrict__ dsum, float* __restrict__ out) {
    out[0] = (float)(*dsum * (1.0 / (double)N_ROWS));
}

// ----------------------------------------------------------------
extern "C" void kernel_launch(void* const* d_in, const int* in_sizes, int n_in,
                              void* d_out, int out_size, void* d_ws, size_t ws_size,
                              hipStream_t stream) {
    const float* X = (const float*)d_in[0];
    float* out = (float*)d_out;

    // ws: Z bf16 [8192*1024] (16MB) | sumexp f32[8192] | dsum double
    ushort_t* Z      = (ushort_t*)d_ws;
    float*    sumexp = (float*)((char*)d_ws + (size_t)N_ROWS * N_DIM * 2);
    double*   dsum   = (double*)((char*)d_ws + (size_t)N_ROWS * N_DIM * 2 + N_ROWS * 4);

    k_normalize<<<N_ROWS / 4, 256, 0, stream>>>(X, Z, sumexp, dsum);

    const int nblk = 32 * 33 / 2;  // 528 triangular 256^2 tiles
    k_gemm_lse<<<nblk, 512, 0, stream>>>(Z, sumexp);

    k_finalize<<<N_ROWS / 4, 256, 0, stream>>>(Z, sumexp, dsum);
    k_store<<<1, 1, 0, stream>>>(dsum, out);
}

// Round 9
// 180.141 us; speedup vs baseline: 1.1841x; 1.1425x over previous
//
#include <hip/hip_runtime.h>

// NT-Xent loss. Round 9 (= round 7/8 resubmitted; infra failures, unmeasured):
//   k_normalize : f32->bf16 Z, zero sumexp, AND dot(z_i,z_0) from raw X
//   k_gemm_lse  : 512 full 256^2 tiles (t 0..511), 8-phase, exactly 2 rounds
//   k_gemm128   : 63 m97-style 128^2 blocks covering tiles (31,16..31)
//   k_finalize  : ONE block: mean(10 + log(sumexp) - 10*dot) -> out
// No same-address atomic storms; fused exp epilogue (lse shift = 10 exact).

typedef unsigned short ushort_t;
typedef __attribute__((ext_vector_type(8))) short short8;
typedef __attribute__((ext_vector_type(4))) float f32x4;

#define N_ROWS 8192
#define N_DIM  1024

__device__ __forceinline__ float bf2f(ushort_t u) {
    return __uint_as_float(((unsigned int)u) << 16);
}
__device__ __forceinline__ ushort_t f2bf(float f) {
    unsigned int u = __float_as_uint(f);
    return (ushort_t)((u + 0x7FFFu + ((u >> 16) & 1u)) >> 16);  // RNE
}

// ---------------------------------------------------------------- kernel 1
// Wave per row (4 rows / 256-thr block). Each wave also loads row 0 (L2
// broadcast) to compute dot(z_i, z_0) = (x_i.x_0)/(|x_i||x_0|) in f32.
__global__ __launch_bounds__(256) void k_normalize(const float* __restrict__ X,
                                                   ushort_t* __restrict__ Z,
                                                   float* __restrict__ sumexp,
                                                   float* __restrict__ dotz) {
    const int lane = threadIdx.x & 63;
    const int wid  = threadIdx.x >> 6;
    const int row  = blockIdx.x * 4 + wid;

    float4 v  = ((const float4*)(X + (size_t)row * N_DIM))[lane];
    float4 v0 = ((const float4*)X)[lane];

    float ss  = v.x * v.x + v.y * v.y + v.z * v.z + v.w * v.w;
    float s0  = v.x * v0.x + v.y * v0.y + v.z * v0.z + v.w * v0.w;
    float ss0 = v0.x * v0.x + v0.y * v0.y + v0.z * v0.z + v0.w * v0.w;
    #pragma unroll
    for (int off = 32; off; off >>= 1) {
        ss  += __shfl_xor(ss, off);
        s0  += __shfl_xor(s0, off);
        ss0 += __shfl_xor(ss0, off);
    }
    float inv  = 1.0f / fmaxf(sqrtf(ss), 1e-8f);
    float inv0 = 1.0f / fmaxf(sqrtf(ss0), 1e-8f);

    ushort4 o;
    o.x = f2bf(v.x * inv);
    o.y = f2bf(v.y * inv);
    o.z = f2bf(v.z * inv);
    o.w = f2bf(v.w * inv);
    ((ushort4*)(Z + (size_t)row * N_DIM))[lane] = o;

    if (lane == 0) {
        sumexp[row] = 0.0f;
        dotz[row]   = s0 * inv * inv0;
    }
}

// ---------------------------------------------------------------- kernel 2
// 256^2 8-phase GEMM (internals frozen from round 6). Grid = 512 full tiles.
#define LDSA(d, h) (((d)*2 + (h)) * 8192)
#define LDSB(d, h) (32768 + ((d)*2 + (h)) * 8192)

#define STAGE(baseoff, panel, h, tt) do {                                         \
    _Pragma("unroll")                                                             \
    for (int p_ = 0; p_ < 2; ++p_) {                                              \
        int rl_ = (p_*8 + w)*8 + srow;                                            \
        const ushort_t* src_ = Z + (size_t)((panel) + (h)*128 + rl_) * N_DIM      \
                                 + (tt)*64 + scol*8;                              \
        __builtin_amdgcn_global_load_lds(                                         \
            (const __attribute__((address_space(1))) void*)src_,                  \
            (__attribute__((address_space(3))) void*)&sh[(baseoff) + (p_*8 + w)*512], \
            16, 0, 0);                                                            \
    }                                                                             \
} while (0)

#define READ_A(d, q) do {                                                         \
    _Pragma("unroll")                                                             \
    for (int mi_ = 0; mi_ < 2; ++mi_)                                             \
        _Pragma("unroll")                                                         \
        for (int ks_ = 0; ks_ < 2; ++ks_) {                                       \
            int rl_ = ((q)*2 + mi_)*16 + lrow;                                    \
            int cu_ = (ks_*4 + kq) ^ (rl_ & 7);                                   \
            afr[mi_][ks_] = *(const short8*)&sh[LDSA(d, wr) + rl_*64 + cu_*8];    \
        }                                                                         \
} while (0)

#define READ_B(d) do {                                                            \
    _Pragma("unroll")                                                             \
    for (int n_ = 0; n_ < 4; ++n_)                                                \
        _Pragma("unroll")                                                         \
        for (int ks_ = 0; ks_ < 2; ++ks_) {                                       \
            int rl_ = (wc & 1)*64 + n_*16 + lrow;                                 \
            int cu_ = (ks_*4 + kq) ^ (rl_ & 7);                                   \
            bfr[n_][ks_] = *(const short8*)&sh[LDSB(d, wc >> 1) + rl_*64 + cu_*8]; \
        }                                                                         \
} while (0)

#define MFMA_Q(q) do {                                                            \
    __builtin_amdgcn_s_setprio(1);                                                \
    _Pragma("unroll")                                                             \
    for (int mi_ = 0; mi_ < 2; ++mi_)                                             \
        _Pragma("unroll")                                                         \
        for (int n_ = 0; n_ < 4; ++n_) {                                          \
            f32x4 t_ = __builtin_amdgcn_mfma_f32_16x16x32_bf16(                   \
                afr[mi_][0], bfr[n_][0], acc[(q)*2 + mi_][n_], 0, 0, 0);          \
            acc[(q)*2 + mi_][n_] = __builtin_amdgcn_mfma_f32_16x16x32_bf16(       \
                afr[mi_][1], bfr[n_][1], t_, 0, 0, 0);                            \
        }                                                                         \
    __builtin_amdgcn_s_setprio(0);                                                \
} while (0)

#define BAR()    __builtin_amdgcn_s_barrier()
#define VMCNT4() asm volatile("s_waitcnt vmcnt(4)" ::: "memory")
#define VMCNT0() asm volatile("s_waitcnt vmcnt(0)" ::: "memory")
#define SBAR0()  __builtin_amdgcn_sched_barrier(0)
#define LGKM0()  asm volatile("s_waitcnt lgkmcnt(0)" ::: "memory")
#define LGKM8()  asm volatile("s_waitcnt lgkmcnt(8)" ::: "memory")

#define PHASE_MFMA(q) do { BAR(); LGKM0(); SBAR0(); MFMA_Q(q); BAR(); } while (0)

__global__ __launch_bounds__(512, 2) void k_gemm_lse(const ushort_t* __restrict__ Z,
                                                     float* __restrict__ sumexp) {
    __shared__ __align__(16) ushort_t sh[65536];  // 128 KiB

    const int tid  = threadIdx.x;
    const int lane = tid & 63;
    const int w    = tid >> 6;
    const int wr   = w >> 2;
    const int wc   = w & 3;
    const int lrow = lane & 15;
    const int kq   = lane >> 4;
    const int srow = lane >> 3;
    const int scol = (lane & 7) ^ srow;

    // XCD chunking over exactly 512 tiles (8*64); triangular decode
    int t = (int)blockIdx.x;
    t = (t & 7) * 64 + (t >> 3);
    int bi = (int)((sqrtf(8.0f * (float)t + 1.0f) - 1.0f) * 0.5f);
    while ((bi + 1) * (bi + 2) / 2 <= t) ++bi;
    while (bi * (bi + 1) / 2 > t) --bi;
    const int bj = t - bi * (bi + 1) / 2;
    const bool diag = (bi == bj);
    const int r0 = bi * 256, c0 = bj * 256;

    f32x4  acc[8][4] = {};
    short8 afr[2][2], bfr[4][2];

    STAGE(LDSB(0,0), c0, 0, 0);
    STAGE(LDSB(0,1), c0, 1, 0);
    STAGE(LDSA(0,0), r0, 0, 0);
    STAGE(LDSA(0,1), r0, 1, 0);
    STAGE(LDSB(1,0), c0, 0, 1);
    STAGE(LDSB(1,1), c0, 1, 1);
    VMCNT4();
    BAR();
    SBAR0();

    #pragma unroll 1
    for (int i = 0; i < 7; ++i) {
        const int t1 = 2*i + 1, t2 = 2*i + 2, t3 = 2*i + 3;
        READ_B(0); READ_A(0,0); STAGE(LDSA(1,0), r0, 0, t1); LGKM8();
        PHASE_MFMA(0);
        READ_A(0,1);            STAGE(LDSA(1,1), r0, 1, t1);
        PHASE_MFMA(1);
        READ_A(0,2);            STAGE(LDSB(0,0), c0, 0, t2);
        PHASE_MFMA(2);
        READ_A(0,3);            STAGE(LDSB(0,1), c0, 1, t2);
        BAR(); LGKM0(); SBAR0(); MFMA_Q(3);
        VMCNT4();
        BAR(); SBAR0();
        READ_B(1); READ_A(1,0); STAGE(LDSA(0,0), r0, 0, t2); LGKM8();
        PHASE_MFMA(0);
        READ_A(1,1);            STAGE(LDSA(0,1), r0, 1, t2);
        PHASE_MFMA(1);
        READ_A(1,2);            STAGE(LDSB(1,0), c0, 0, t3);
        PHASE_MFMA(2);
        READ_A(1,3);            STAGE(LDSB(1,1), c0, 1, t3);
        BAR(); LGKM0(); SBAR0(); MFMA_Q(3);
        VMCNT4();
        BAR(); SBAR0();
    }

    READ_B(0); READ_A(0,0); STAGE(LDSA(1,0), r0, 0, 15); LGKM8();
    PHASE_MFMA(0);
    READ_A(0,1);            STAGE(LDSA(1,1), r0, 1, 15);
    PHASE_MFMA(1);
    READ_A(0,2);
    PHASE_MFMA(2);
    READ_A(0,3);
    BAR(); LGKM0(); SBAR0(); MFMA_Q(3); VMCNT0(); BAR(); SBAR0();
    READ_B(1); READ_A(1,0);
    PHASE_MFMA(0);
    READ_A(1,1);
    PHASE_MFMA(1);
    READ_A(1,2);
    PHASE_MFMA(2);
    READ_A(1,3);
    LGKM0(); SBAR0(); MFMA_Q(3);

    // fused epilogue: e = exp(10c-10); rows always, cols if !diag
    float rp[8][4];
    float cp[4] = {0.f, 0.f, 0.f, 0.f};
    #pragma unroll
    for (int m = 0; m < 8; ++m)
        #pragma unroll
        for (int r = 0; r < 4; ++r) rp[m][r] = 0.f;

    #pragma unroll
    for (int m = 0; m < 8; ++m)
        #pragma unroll
        for (int n = 0; n < 4; ++n)
            #pragma unroll
            for (int r = 0; r < 4; ++r) {
                float e = __expf(acc[m][n][r] * 10.0f - 10.0f);
                rp[m][r] += e;
                cp[n]    += e;
            }

    #pragma unroll
    for (int m = 0; m < 8; ++m) {
        #pragma unroll
        for (int off = 1; off < 16; off <<= 1)
            #pragma unroll
            for (int r = 0; r < 4; ++r) rp[m][r] += __shfl_xor(rp[m][r], off);
        if (lrow == 0) {
            int rowbase = r0 + wr * 128 + m * 16 + kq * 4;
            #pragma unroll
            for (int r = 0; r < 4; ++r) atomicAdd(&sumexp[rowbase + r], rp[m][r]);
        }
    }

    if (!diag) {
        #pragma unroll
        for (int n = 0; n < 4; ++n) {
            cp[n] += __shfl_xor(cp[n], 16);
            cp[n] += __shfl_xor(cp[n], 32);
        }
        if (kq == 0) {
            #pragma unroll
            for (int n = 0; n < 4; ++n)
                atomicAdd(&sumexp[c0 + wc * 64 + n * 16 + lrow], cp[n]);
        }
    }
}

// ---------------------------------------------------------------- kernel 3
// m97-style 128^2 GEMM (round-2 verified body). Covers the 16 leftover 256^2
// tiles (31, 16..31) as 63 sub-tiles: gid 0..30 -> (62, 32+gid);
// gid 31..62 -> (63, gid+1). (Diag (62,62),(63,63); (63,62) col-path covers
// the (62,63) transpose.)
__global__ __launch_bounds__(256) void k_gemm128(const ushort_t* __restrict__ Z,
                                                 float* __restrict__ sumexp) {
    __shared__ ushort_t As[128 * 32];
    __shared__ ushort_t Bs[128 * 32];

    const int gid = blockIdx.x;
    const int bi = (gid < 31) ? 62 : 63;
    const int bj = (gid < 31) ? (32 + gid) : (gid + 1);
    const bool diag = (bi == bj);

    const int tid  = threadIdx.x;
    const int lane = tid & 63;
    const int w    = tid >> 6;
    const int wr   = w >> 1;
    const int wc   = w & 1;
    const int r0   = bi * 128;
    const int c0   = bj * 128;

    const int lrow = lane & 15;
    const int kq   = lane >> 4;

    f32x4 acc[4][4] = {};

    for (int kt = 0; kt < N_DIM; kt += 32) {
        #pragma unroll
        for (int p = 0; p < 2; ++p) {
            int idx  = p * 256 + tid;
            int row  = idx >> 2;
            int kq4  = idx & 3;
            const ushort_t* ga = Z + (size_t)(r0 + row) * N_DIM + kt + kq4 * 8;
            const ushort_t* gb = Z + (size_t)(c0 + row) * N_DIM + kt + kq4 * 8;
            __builtin_amdgcn_global_load_lds(
                (const __attribute__((address_space(1))) void*)ga,
                (__attribute__((address_space(3))) void*)&As[(p * 256 + w * 64) * 8],
                16, 0, 0);
            __builtin_amdgcn_global_load_lds(
                (const __attribute__((address_space(1))) void*)gb,
                (__attribute__((address_space(3))) void*)&Bs[(p * 256 + w * 64) * 8],
                16, 0, 0);
        }
        __syncthreads();

        short8 a[4], b[4];
        #pragma unroll
        for (int m = 0; m < 4; ++m)
            a[m] = *(const short8*)&As[(wr * 64 + m * 16 + lrow) * 32 + kq * 8];
        #pragma unroll
        for (int n = 0; n < 4; ++n)
            b[n] = *(const short8*)&Bs[(wc * 64 + n * 16 + lrow) * 32 + kq * 8];

        #pragma unroll
        for (int m = 0; m < 4; ++m)
            #pragma unroll
            for (int n = 0; n < 4; ++n)
                acc[m][n] = __builtin_amdgcn_mfma_f32_16x16x32_bf16(
                    a[m], b[n], acc[m][n], 0, 0, 0);
        __syncthreads();
    }

    float rp[4][4] = {};
    float cp[4]    = {};
    #pragma unroll
    for (int m = 0; m < 4; ++m)
        #pragma unroll
        for (int n = 0; n < 4; ++n)
            #pragma unroll
            for (int r = 0; r < 4; ++r) {
                float e = __expf(acc[m][n][r] * 10.0f - 10.0f);
                rp[m][r] += e;
                cp[n]    += e;
            }

    #pragma unroll
    for (int m = 0; m < 4; ++m) {
        #pragma unroll
        for (int off = 1; off < 16; off <<= 1)
            #pragma unroll
            for (int r = 0; r < 4; ++r) rp[m][r] += __shfl_xor(rp[m][r], off);
        if (lrow == 0) {
            int rowbase = r0 + wr * 64 + m * 16 + kq * 4;
            #pragma unroll
            for (int r = 0; r < 4; ++r) atomicAdd(&sumexp[rowbase + r], rp[m][r]);
        }
    }

    if (!diag) {
        #pragma unroll
        for (int n = 0; n < 4; ++n) {
            cp[n] += __shfl_xor(cp[n], 16);
            cp[n] += __shfl_xor(cp[n], 32);
        }
        if (kq == 0) {
            #pragma unroll
            for (int n = 0; n < 4; ++n)
                atomicAdd(&sumexp[c0 + wc * 64 + n * 16 + lrow], cp[n]);
        }
    }
}

// ---------------------------------------------------------------- kernel 4
// One block: mean over rows of 10 + log(sumexp) - 10*dot. No atomics.
__global__ __launch_bounds__(1024) void k_finalize(const float* __restrict__ sumexp,
                                                   const float* __restrict__ dotz,
                                                   float* __restrict__ out) {
    double s = 0.0;
    for (int r = threadIdx.x; r < N_ROWS; r += 1024)
        s += (double)(10.0f + logf(sumexp[r]) - 10.0f * dotz[r]);

    const int lane = threadIdx.x & 63;
    const int wid  = threadIdx.x >> 6;
    #pragma unroll
    for (int off = 32; off; off >>= 1) s += __shfl_down(s, off);

    __shared__ double sh[16];
    if (lane == 0) sh[wid] = s;
    __syncthreads();
    if (threadIdx.x == 0) {
        double tot = 0.0;
        #pragma unroll
        for (int i = 0; i < 16; ++i) tot += sh[i];
        out[0] = (float)(tot / (double)N_ROWS);
    }
}

// ----------------------------------------------------------------
extern "C" void kernel_launch(void* const* d_in, const int* in_sizes, int n_in,
                              void* d_out, int out_size, void* d_ws, size_t ws_size,
                              hipStream_t stream) {
    const float* X = (const float*)d_in[0];
    float* out = (float*)d_out;

    // ws: Z bf16 [8192*1024] (16MB) | sumexp f32[8192] | dotz f32[8192]
    ushort_t* Z      = (ushort_t*)d_ws;
    float*    sumexp = (float*)((char*)d_ws + (size_t)N_ROWS * N_DIM * 2);
    float*    dotz   = sumexp + N_ROWS;

    k_normalize<<<N_ROWS / 4, 256, 0, stream>>>(X, Z, sumexp, dotz);
    k_gemm_lse<<<512, 512, 0, stream>>>(Z, sumexp);
    k_gemm128<<<63, 256, 0, stream>>>(Z, sumexp);
    k_finalize<<<1, 1024, 0, stream>>>(sumexp, dotz, out);
}

// Round 10
// 176.039 us; speedup vs baseline: 1.2117x; 1.0233x over previous
//
#include <hip/hip_runtime.h>

// NT-Xent loss. Round 10: persistent 2-tile 256^2 8-phase GEMM.
//   k_normalize : f32->bf16 Z, zero sumexp, AND dot(z_i,z_0) from raw X
//   k_gemm_lse  : 256 persistent blocks x 2 tiles (t, t+256) of the 512 full
//                 256^2 triangular tiles; tile-2 prologue issued inside
//                 tile-1 tail; tile-1 atomics deferred past tile-2's vmcnt.
//   k_gemm128   : 63 m97-style 128^2 blocks covering tiles (31,16..31)
//   k_finalize  : ONE block: mean(10 + log(sumexp) - 10*dot) -> out

typedef unsigned short ushort_t;
typedef __attribute__((ext_vector_type(8))) short short8;
typedef __attribute__((ext_vector_type(4))) float f32x4;

#define N_ROWS 8192
#define N_DIM  1024

__device__ __forceinline__ float bf2f(ushort_t u) {
    return __uint_as_float(((unsigned int)u) << 16);
}
__device__ __forceinline__ ushort_t f2bf(float f) {
    unsigned int u = __float_as_uint(f);
    return (ushort_t)((u + 0x7FFFu + ((u >> 16) & 1u)) >> 16);  // RNE
}

// ---------------------------------------------------------------- kernel 1
__global__ __launch_bounds__(256) void k_normalize(const float* __restrict__ X,
                                                   ushort_t* __restrict__ Z,
                                                   float* __restrict__ sumexp,
                                                   float* __restrict__ dotz) {
    const int lane = threadIdx.x & 63;
    const int wid  = threadIdx.x >> 6;
    const int row  = blockIdx.x * 4 + wid;

    float4 v  = ((const float4*)(X + (size_t)row * N_DIM))[lane];
    float4 v0 = ((const float4*)X)[lane];

    float ss  = v.x * v.x + v.y * v.y + v.z * v.z + v.w * v.w;
    float s0  = v.x * v0.x + v.y * v0.y + v.z * v0.z + v.w * v0.w;
    float ss0 = v0.x * v0.x + v0.y * v0.y + v0.z * v0.z + v0.w * v0.w;
    #pragma unroll
    for (int off = 32; off; off >>= 1) {
        ss  += __shfl_xor(ss, off);
        s0  += __shfl_xor(s0, off);
        ss0 += __shfl_xor(ss0, off);
    }
    float inv  = 1.0f / fmaxf(sqrtf(ss), 1e-8f);
    float inv0 = 1.0f / fmaxf(sqrtf(ss0), 1e-8f);

    ushort4 o;
    o.x = f2bf(v.x * inv);
    o.y = f2bf(v.y * inv);
    o.z = f2bf(v.z * inv);
    o.w = f2bf(v.w * inv);
    ((ushort4*)(Z + (size_t)row * N_DIM))[lane] = o;

    if (lane == 0) {
        sumexp[row] = 0.0f;
        dotz[row]   = s0 * inv * inv0;
    }
}

// ---------------------------------------------------------------- kernel 2
#define LDSA(d, h) (((d)*2 + (h)) * 8192)
#define LDSB(d, h) (32768 + ((d)*2 + (h)) * 8192)

#define STAGE(baseoff, panel, h, tt) do {                                         \
    _Pragma("unroll")                                                             \
    for (int p_ = 0; p_ < 2; ++p_) {                                              \
        int rl_ = (p_*8 + w)*8 + srow;                                            \
        const ushort_t* src_ = Z + (size_t)((panel) + (h)*128 + rl_) * N_DIM      \
                                 + (tt)*64 + scol*8;                              \
        __builtin_amdgcn_global_load_lds(                                         \
            (const __attribute__((address_space(1))) void*)src_,                  \
            (__attribute__((address_space(3))) void*)&sh[(baseoff) + (p_*8 + w)*512], \
            16, 0, 0);                                                            \
    }                                                                             \
} while (0)

#define READ_A(d, q) do {                                                         \
    _Pragma("unroll")                                                             \
    for (int mi_ = 0; mi_ < 2; ++mi_)                                             \
        _Pragma("unroll")                                                         \
        for (int ks_ = 0; ks_ < 2; ++ks_) {                                       \
            int rl_ = ((q)*2 + mi_)*16 + lrow;                                    \
            int cu_ = (ks_*4 + kq) ^ (rl_ & 7);                                   \
            afr[mi_][ks_] = *(const short8*)&sh[LDSA(d, wr) + rl_*64 + cu_*8];    \
        }                                                                         \
} while (0)

#define READ_B(d) do {                                                            \
    _Pragma("unroll")                                                             \
    for (int n_ = 0; n_ < 4; ++n_)                                                \
        _Pragma("unroll")                                                         \
        for (int ks_ = 0; ks_ < 2; ++ks_) {                                       \
            int rl_ = (wc & 1)*64 + n_*16 + lrow;                                 \
            int cu_ = (ks_*4 + kq) ^ (rl_ & 7);                                   \
            bfr[n_][ks_] = *(const short8*)&sh[LDSB(d, wc >> 1) + rl_*64 + cu_*8]; \
        }                                                                         \
} while (0)

#define MFMA_Q(q) do {                                                            \
    __builtin_amdgcn_s_setprio(1);                                                \
    _Pragma("unroll")                                                             \
    for (int mi_ = 0; mi_ < 2; ++mi_)                                             \
        _Pragma("unroll")                                                         \
        for (int n_ = 0; n_ < 4; ++n_) {                                          \
            f32x4 t_ = __builtin_amdgcn_mfma_f32_16x16x32_bf16(                   \
                afr[mi_][0], bfr[n_][0], acc[(q)*2 + mi_][n_], 0, 0, 0);          \
            acc[(q)*2 + mi_][n_] = __builtin_amdgcn_mfma_f32_16x16x32_bf16(       \
                afr[mi_][1], bfr[n_][1], t_, 0, 0, 0);                            \
        }                                                                         \
    __builtin_amdgcn_s_setprio(0);                                                \
} while (0)

#define BAR()    __builtin_amdgcn_s_barrier()
#define VMCNT4() asm volatile("s_waitcnt vmcnt(4)" ::: "memory")
#define VMCNT0() asm volatile("s_waitcnt vmcnt(0)" ::: "memory")
#define SBAR0()  __builtin_amdgcn_sched_barrier(0)
#define LGKM0()  asm volatile("s_waitcnt lgkmcnt(0)" ::: "memory")
#define LGKM8()  asm volatile("s_waitcnt lgkmcnt(8)" ::: "memory")

#define PHASE_MFMA(q) do { BAR(); LGKM0(); SBAR0(); MFMA_Q(q); BAR(); } while (0)

// exp + partial-sum computation into rp/cp (VALU + shuffles, no atomics)
#define EPI_COMPUTE() do {                                                        \
    _Pragma("unroll")                                                             \
    for (int m = 0; m < 8; ++m)                                                   \
        _Pragma("unroll")                                                         \
        for (int r = 0; r < 4; ++r) rp[m][r] = 0.f;                               \
    _Pragma("unroll")                                                             \
    for (int n = 0; n < 4; ++n) cp[n] = 0.f;                                      \
    _Pragma("unroll")                                                             \
    for (int m = 0; m < 8; ++m)                                                   \
        _Pragma("unroll")                                                         \
        for (int n = 0; n < 4; ++n)                                               \
            _Pragma("unroll")                                                     \
            for (int r = 0; r < 4; ++r) {                                         \
                float e = __expf(acc[m][n][r] * 10.0f - 10.0f);                   \
                rp[m][r] += e;                                                    \
                cp[n]    += e;                                                    \
            }                                                                     \
    _Pragma("unroll")                                                             \
    for (int m = 0; m < 8; ++m)                                                   \
        _Pragma("unroll")                                                         \
        for (int off = 1; off < 16; off <<= 1)                                    \
            _Pragma("unroll")                                                     \
            for (int r = 0; r < 4; ++r) rp[m][r] += __shfl_xor(rp[m][r], off);    \
    _Pragma("unroll")                                                             \
    for (int n = 0; n < 4; ++n) {                                                 \
        cp[n] += __shfl_xor(cp[n], 16);                                           \
        cp[n] += __shfl_xor(cp[n], 32);                                           \
    }                                                                             \
} while (0)

// atomics for previously computed rp/cp at geometry (r0v, c0v, diagv)
#define EPI_ATOMIC(r0v, c0v, diagv) do {                                          \
    _Pragma("unroll")                                                             \
    for (int m = 0; m < 8; ++m) {                                                 \
        if (lrow == 0) {                                                          \
            int rowbase = (r0v) + wr * 128 + m * 16 + kq * 4;                     \
            _Pragma("unroll")                                                     \
            for (int r = 0; r < 4; ++r)                                           \
                atomicAdd(&sumexp[rowbase + r], rp[m][r]);                        \
        }                                                                         \
    }                                                                             \
    if (!(diagv) && kq == 0) {                                                    \
        _Pragma("unroll")                                                         \
        for (int n = 0; n < 4; ++n)                                               \
            atomicAdd(&sumexp[(c0v) + wc * 64 + n * 16 + lrow], cp[n]);           \
    }                                                                             \
} while (0)

__global__ __launch_bounds__(512, 2) void k_gemm_lse(const ushort_t* __restrict__ Z,
                                                     float* __restrict__ sumexp) {
    __shared__ __align__(16) ushort_t sh[65536];  // 128 KiB

    const int tid  = threadIdx.x;
    const int lane = tid & 63;
    const int w    = tid >> 6;
    const int wr   = w >> 2;
    const int wc   = w & 3;
    const int lrow = lane & 15;
    const int kq   = lane >> 4;
    const int srow = lane >> 3;
    const int scol = (lane & 7) ^ srow;

    // persistent: block handles tiles l and l+256 (XCD-chunked, 256 = 8*32)
    const int l = ((int)blockIdx.x & 7) * 32 + ((int)blockIdx.x >> 3);
    int R0[2], C0[2];
    bool DIAG[2];
    #pragma unroll
    for (int k = 0; k < 2; ++k) {
        int t = l + k * 256;
        int bi = (int)((sqrtf(8.0f * (float)t + 1.0f) - 1.0f) * 0.5f);
        while ((bi + 1) * (bi + 2) / 2 <= t) ++bi;
        while (bi * (bi + 1) / 2 > t) --bi;
        int bj = t - bi * (bi + 1) / 2;
        R0[k] = bi * 256;
        C0[k] = bj * 256;
        DIAG[k] = (bi == bj);
    }

    f32x4  acc[8][4];
    short8 afr[2][2], bfr[4][2];
    float  rp[8][4], cp[4];

    // tile-0 prologue: d0 (B0,B1,A0,A1), d1 (B0,B1 of K-tile 1); 12 loads.
    STAGE(LDSB(0,0), C0[0], 0, 0);
    STAGE(LDSB(0,1), C0[0], 1, 0);
    STAGE(LDSA(0,0), R0[0], 0, 0);
    STAGE(LDSA(0,1), R0[0], 1, 0);
    STAGE(LDSB(1,0), C0[0], 0, 1);
    STAGE(LDSB(1,1), C0[0], 1, 1);

    #pragma unroll
    for (int tile = 0; tile < 2; ++tile) {
        const int r0 = R0[tile], c0 = C0[tile];

        VMCNT4();   // 8 oldest (= all of this tile's d0) complete
        BAR();
        SBAR0();

        // deferred tile-0 atomics: issued as NEWEST vmem ops; they complete
        // during ph0-3 and every later vmcnt(4) leaves only the 4 newest
        // stage-loads outstanding, so the ledger semantics are preserved.
        if (tile == 1) EPI_ATOMIC(R0[0], C0[0], DIAG[0]);

        #pragma unroll
        for (int m = 0; m < 8; ++m)
            #pragma unroll
            for (int n = 0; n < 4; ++n)
                acc[m][n] = (f32x4){0.f, 0.f, 0.f, 0.f};

        #pragma unroll 1
        for (int i = 0; i < 7; ++i) {
            const int t1 = 2*i + 1, t2 = 2*i + 2, t3 = 2*i + 3;
            READ_B(0); READ_A(0,0); STAGE(LDSA(1,0), r0, 0, t1); LGKM8();
            PHASE_MFMA(0);
            READ_A(0,1);            STAGE(LDSA(1,1), r0, 1, t1);
            PHASE_MFMA(1);
            READ_A(0,2);            STAGE(LDSB(0,0), c0, 0, t2);
            PHASE_MFMA(2);
            READ_A(0,3);            STAGE(LDSB(0,1), c0, 1, t2);
            BAR(); LGKM0(); SBAR0(); MFMA_Q(3);
            VMCNT4();
            BAR(); SBAR0();
            READ_B(1); READ_A(1,0); STAGE(LDSA(0,0), r0, 0, t2); LGKM8();
            PHASE_MFMA(0);
            READ_A(1,1);            STAGE(LDSA(0,1), r0, 1, t2);
            PHASE_MFMA(1);
            READ_A(1,2);            STAGE(LDSB(1,0), c0, 0, t3);
            PHASE_MFMA(2);
            READ_A(1,3);            STAGE(LDSB(1,1), c0, 1, t3);
            BAR(); LGKM0(); SBAR0(); MFMA_Q(3);
            VMCNT4();
            BAR(); SBAR0();
        }

        // epilogue iteration: K-tiles 14 (d0) and 15 (d1)
        READ_B(0); READ_A(0,0); STAGE(LDSA(1,0), r0, 0, 15); LGKM8();
        PHASE_MFMA(0);
        READ_A(0,1);            STAGE(LDSA(1,1), r0, 1, 15);
        PHASE_MFMA(1);
        READ_A(0,2);
        PHASE_MFMA(2);
        READ_A(0,3);
        BAR(); LGKM0(); SBAR0(); MFMA_Q(3); VMCNT0(); BAR(); SBAR0();
        READ_B(1); READ_A(1,0);
        PHASE_MFMA(0);
        READ_A(1,1);
        PHASE_MFMA(1);
        READ_A(1,2);
        PHASE_MFMA(2);
        READ_A(1,3);
        LGKM0(); SBAR0(); MFMA_Q(3);
        BAR();   // all waves done reading d1 -> LDS free for next tile

        if (tile == 0) {
            // tile-1 prologue issued NOW; latency hides under EPI_COMPUTE
            STAGE(LDSB(0,0), C0[1], 0, 0);
            STAGE(LDSB(0,1), C0[1], 1, 0);
            STAGE(LDSA(0,0), R0[1], 0, 0);
            STAGE(LDSA(0,1), R0[1], 1, 0);
            STAGE(LDSB(1,0), C0[1], 0, 1);
            STAGE(LDSB(1,1), C0[1], 1, 1);
        }

        EPI_COMPUTE();   // exp + shuffle reduce into rp/cp (no vmem)
    }

    EPI_ATOMIC(R0[1], C0[1], DIAG[1]);
}

// ---------------------------------------------------------------- kernel 3
// m97-style 128^2 GEMM covering leftover tiles (31, 16..31) as 63 sub-tiles.
__global__ __launch_bounds__(256) void k_gemm128(const ushort_t* __restrict__ Z,
                                                 float* __restrict__ sumexp) {
    __shared__ ushort_t As[128 * 32];
    __shared__ ushort_t Bs[128 * 32];

    const int gid = blockIdx.x;
    const int bi = (gid < 31) ? 62 : 63;
    const int bj = (gid < 31) ? (32 + gid) : (gid + 1);
    const bool diag = (bi == bj);

    const int tid  = threadIdx.x;
    const int lane = tid & 63;
    const int w    = tid >> 6;
    const int wr   = w >> 1;
    const int wc   = w & 1;
    const int r0   = bi * 128;
    const int c0   = bj * 128;

    const int lrow = lane & 15;
    const int kq   = lane >> 4;

    f32x4 acc[4][4] = {};

    for (int kt = 0; kt < N_DIM; kt += 32) {
        #pragma unroll
        for (int p = 0; p < 2; ++p) {
            int idx  = p * 256 + tid;
            int row  = idx >> 2;
            int kq4  = idx & 3;
            const ushort_t* ga = Z + (size_t)(r0 + row) * N_DIM + kt + kq4 * 8;
            const ushort_t* gb = Z + (size_t)(c0 + row) * N_DIM + kt + kq4 * 8;
            __builtin_amdgcn_global_load_lds(
                (const __attribute__((address_space(1))) void*)ga,
                (__attribute__((address_space(3))) void*)&As[(p * 256 + w * 64) * 8],
                16, 0, 0);
            __builtin_amdgcn_global_load_lds(
                (const __attribute__((address_space(1))) void*)gb,
                (__attribute__((address_space(3))) void*)&Bs[(p * 256 + w * 64) * 8],
                16, 0, 0);
        }
        __syncthreads();

        short8 a[4], b[4];
        #pragma unroll
        for (int m = 0; m < 4; ++m)
            a[m] = *(const short8*)&As[(wr * 64 + m * 16 + lrow) * 32 + kq * 8];
        #pragma unroll
        for (int n = 0; n < 4; ++n)
            b[n] = *(const short8*)&Bs[(wc * 64 + n * 16 + lrow) * 32 + kq * 8];

        #pragma unroll
        for (int m = 0; m < 4; ++m)
            #pragma unroll
            for (int n = 0; n < 4; ++n)
                acc[m][n] = __builtin_amdgcn_mfma_f32_16x16x32_bf16(
                    a[m], b[n], acc[m][n], 0, 0, 0);
        __syncthreads();
    }

    float rp[4][4] = {};
    float cp[4]    = {};
    #pragma unroll
    for (int m = 0; m < 4; ++m)
        #pragma unroll
        for (int n = 0; n < 4; ++n)
            #pragma unroll
            for (int r = 0; r < 4; ++r) {
                float e = __expf(acc[m][n][r] * 10.0f - 10.0f);
                rp[m][r] += e;
                cp[n]    += e;
            }

    #pragma unroll
    for (int m = 0; m < 4; ++m) {
        #pragma unroll
        for (int off = 1; off < 16; off <<= 1)
            #pragma unroll
            for (int r = 0; r < 4; ++r) rp[m][r] += __shfl_xor(rp[m][r], off);
        if (lrow == 0) {
            int rowbase = r0 + wr * 64 + m * 16 + kq * 4;
            #pragma unroll
            for (int r = 0; r < 4; ++r) atomicAdd(&sumexp[rowbase + r], rp[m][r]);
        }
    }

    if (!diag) {
        #pragma unroll
        for (int n = 0; n < 4; ++n) {
            cp[n] += __shfl_xor(cp[n], 16);
            cp[n] += __shfl_xor(cp[n], 32);
        }
        if (kq == 0) {
            #pragma unroll
            for (int n = 0; n < 4; ++n)
                atomicAdd(&sumexp[c0 + wc * 64 + n * 16 + lrow], cp[n]);
        }
    }
}

// ---------------------------------------------------------------- kernel 4
__global__ __launch_bounds__(1024) void k_finalize(const float* __restrict__ sumexp,
                                                   const float* __restrict__ dotz,
                                                   float* __restrict__ out) {
    double s = 0.0;
    for (int r = threadIdx.x; r < N_ROWS; r += 1024)
        s += (double)(10.0f + logf(sumexp[r]) - 10.0f * dotz[r]);

    const int lane = threadIdx.x & 63;
    const int wid  = threadIdx.x >> 6;
    #pragma unroll
    for (int off = 32; off; off >>= 1) s += __shfl_down(s, off);

    __shared__ double sh[16];
    if (lane == 0) sh[wid] = s;
    __syncthreads();
    if (threadIdx.x == 0) {
        double tot = 0.0;
        #pragma unroll
        for (int i = 0; i < 16; ++i) tot += sh[i];
        out[0] = (float)(tot / (double)N_ROWS);
    }
}

// ----------------------------------------------------------------
extern "C" void kernel_launch(void* const* d_in, const int* in_sizes, int n_in,
                              void* d_out, int out_size, void* d_ws, size_t ws_size,
                              hipStream_t stream) {
    const float* X = (const float*)d_in[0];
    float* out = (float*)d_out;

    // ws: Z bf16 [8192*1024] (16MB) | sumexp f32[8192] | dotz f32[8192]
    ushort_t* Z      = (ushort_t*)d_ws;
    float*    sumexp = (float*)((char*)d_ws + (size_t)N_ROWS * N_DIM * 2);
    float*    dotz   = sumexp + N_ROWS;

    k_normalize<<<N_ROWS / 4, 256, 0, stream>>>(X, Z, sumexp, dotz);
    k_gemm_lse<<<256, 512, 0, stream>>>(Z, sumexp);
    k_gemm128<<<63, 256, 0, stream>>>(Z, sumexp);
    k_finalize<<<1, 1024, 0, stream>>>(sumexp, dotz, out);
}